// Round 4
// baseline (197.453 us; speedup 1.0000x reference)
//
#include <hip/hip_runtime.h>
#include <hip/hip_bf16.h>
#include <math.h>

// FreqActivation — output is the REAL part of the complex64 ref (float32 cast),
// out[b,h,w,c] = relu(amp)*cos(pi*tanh(ph)) gathered from
//   (h,w) if h+w<=256, else (256-h,256-w)  [conj doesn't affect the real part].
//
// Scatter formulation: each thread handles a SOURCE row position with
// h+w <= 256, reads its 8 input floats ONCE, and writes the identical result
// float4 to both destinations:
//   - out[b,h,w,c4]                     (always)
//   - out[b,256-h,256-w,c4]             (iff h+w<=255 && h>=1 && w>=1)
// Coverage: every output element written exactly once (mirror dest has
// h'+w' = 512-(h+w) >= 257; borders/diagonal h+w=256 have no mirror).
// This halves read traffic vs the gather version (67 MB reads + 67 MB writes).
//
// Fast tanh: t = exp2f-based __expf(2x); tanh = (t-1)/(t+1). Abs err ~1e-7.

#define PI_F 3.14159265358979323846f

__device__ __forceinline__ float act_real(float amp_raw, float ph_raw) {
    const float t  = __expf(2.0f * ph_raw);          // e^{2x}; inf/0 at extremes -> tanh = +/-1
    const float th = (t - 1.0f) * __frcp_rn(t + 1.0f);
    return fmaxf(amp_raw, 0.0f) * __cosf(PI_F * th);
}

__global__ __launch_bounds__(256) void freq_act_kernel(
    const float* __restrict__ in, float* __restrict__ out, int n_vec4)
{
    const int tid = blockIdx.x * 256 + threadIdx.x;
    if (tid >= n_vec4) return;

    const int c4 = tid & 7;           // which output float4 within the 32-float row
    const int w  = (tid >> 3)  & 255;
    const int h  = (tid >> 11) & 255;
    const int b  = tid >> 19;
    if (b >= 8) return;

    const int sum = h + w;
    if (sum > 256) return;            // bottom half handled by mirror stores

    // input row: 64 floats; this thread needs floats [c4*8, c4*8+8)
    const float* src = in + (((size_t)((b * 256 + h) * 256 + w)) << 6) + (c4 << 3);
    const float4 v0 = *reinterpret_cast<const float4*>(src);
    const float4 v1 = *reinterpret_cast<const float4*>(src + 4);

    float4 o;
    o.x = act_real(v0.x, v0.y);
    o.y = act_real(v0.z, v0.w);
    o.z = act_real(v1.x, v1.y);
    o.w = act_real(v1.z, v1.w);

    float4* outv = reinterpret_cast<float4*>(out);
    outv[tid] = o;                    // top destination (coalesced)

    if (sum <= 255 && h >= 1 && w >= 1) {
        // mirror destination: same value (conj leaves real part unchanged)
        const size_t mvec = (((size_t)((b * 256 + (256 - h)) * 256 + (256 - w))) << 3) + c4;
        outv[mvec] = o;
    }
}

extern "C" void kernel_launch(void* const* d_in, const int* in_sizes, int n_in,
                              void* d_out, int out_size, void* d_ws, size_t ws_size,
                              hipStream_t stream)
{
    const float* in = (const float*)d_in[0];
    float* out = (float*)d_out;

    const int n_vec4 = out_size / 4;          // 4,194,304
    const int block = 256;
    const int grid = (n_vec4 + block - 1) / block;

    freq_act_kernel<<<grid, block, 0, stream>>>(in, out, n_vec4);
}

// Round 5
// 195.770 us; speedup vs baseline: 1.0086x; 1.0086x over previous
//
#include <hip/hip_runtime.h>
#include <hip/hip_bf16.h>
#include <math.h>

// FreqActivation — output is the REAL part of the complex64 ref (float32 cast):
// out[b,h,w,c] = relu(amp)*cos(pi*tanh(ph)) gathered from
//   (h,w) if h+w <= 256, else (256-h,256-w)   [conj doesn't affect real part].
//
// Gather formulation (R3 structure): duplicate mirror reads are L3-absorbed
// (input 134 MB << 256 MiB L3), both loads and stores fully coalesced, no
// idle threads. R4's scatter variant measured neutral-to-worse.
//
// Transcendentals via HW ops only:
//   t  = __expf(2x)                      -> v_exp_f32
//   th = (t-1) * v_rcp(t+1)              -> tanh(x), abs err ~1e-7
//   cos(pi*th) = v_cos(0.5*th revs)      -> skips pi-mul + range reduction
// |0.5*th| <= 0.5 — inside v_cos's native range.

__device__ __forceinline__ float act_real(float amp_raw, float ph_raw) {
    const float t  = __expf(2.0f * ph_raw);
    const float th = (t - 1.0f) * __builtin_amdgcn_rcpf(t + 1.0f);
    return fmaxf(amp_raw, 0.0f) * __builtin_amdgcn_cosf(0.5f * th);
}

__global__ __launch_bounds__(256) void freq_act_kernel(
    const float* __restrict__ in, float* __restrict__ out, int n_vec4)
{
    const int tid = blockIdx.x * 256 + threadIdx.x;
    if (tid >= n_vec4) return;

    const int c4 = tid & 7;           // which output float4 within the 32-float row
    const int w  = (tid >> 3)  & 255;
    const int h  = (tid >> 11) & 255;
    const int b  = tid >> 19;
    if (b >= 8) return;

    const bool top = (h + w) <= 256;
    const int  sh  = top ? h : 256 - h;
    const int  sw  = top ? w : 256 - w;

    // input row: 64 floats; this thread needs floats [c4*8, c4*8+8)
    const float* src = in + (((size_t)((b * 256 + sh) * 256 + sw)) << 6) + (c4 << 3);
    const float4 v0 = *reinterpret_cast<const float4*>(src);
    const float4 v1 = *reinterpret_cast<const float4*>(src + 4);

    float4 o;
    o.x = act_real(v0.x, v0.y);
    o.y = act_real(v0.z, v0.w);
    o.z = act_real(v1.x, v1.y);
    o.w = act_real(v1.z, v1.w);
    *reinterpret_cast<float4*>(out + ((size_t)tid << 2)) = o;
}

extern "C" void kernel_launch(void* const* d_in, const int* in_sizes, int n_in,
                              void* d_out, int out_size, void* d_ws, size_t ws_size,
                              hipStream_t stream)
{
    const float* in = (const float*)d_in[0];
    float* out = (float*)d_out;

    const int n_vec4 = out_size / 4;          // 4,194,304
    const int block = 256;
    const int grid = (n_vec4 + block - 1) / block;

    freq_act_kernel<<<grid, block, 0, stream>>>(in, out, n_vec4);
}